// Round 9
// baseline (229.523 us; speedup 1.0000x reference)
//
#include <hip/hip_runtime.h>
#include <cstdint>
#include <cstddef>

// ---------------------------------------------------------------------------
// MemoryLayer on MI355X: bf16 MFMA GEMMs + flash attention (no-max softmax,
// 32x32 MFMA, fragment-major K/V global layout -> conflict-free LDS).
// B=2, S=4096, D=512, W=256, H=4, DH=64.
// Round-9 delta vs round-8 (passed, 223us): attention rewritten as
// SINGLE-WAVE blocks with counted-vmcnt staging (no __syncthreads at all):
// each wave stages its own K+V tile via global_load_lds and waits
// s_waitcnt vmcnt(8) so next-tile loads stay in flight across compute.
// l-sum via P@ones MFMA (VALU -> matrix pipe). Grid (64,8,kvs), 64 thr.
// ---------------------------------------------------------------------------

#define GAS(p) ((const __attribute__((address_space(1))) void*)(p))
#define LAS(p) ((__attribute__((address_space(3))) void*)(p))

typedef __attribute__((ext_vector_type(8))) short bfrag;    // 8 x bf16
typedef __attribute__((ext_vector_type(4))) float facc;     // 16x16 acc
typedef __attribute__((ext_vector_type(16))) float facc16;  // 32x32 acc
typedef uint16_t u16;

__device__ __forceinline__ u16 f2bf(float f) {
  uint32_t u = __float_as_uint(f);
  u += 0x7fffu + ((u >> 16) & 1u);          // RNE
  return (u16)(u >> 16);
}
__device__ __forceinline__ float bf2f(u16 h) {
  return __uint_as_float((uint32_t)h << 16);
}
__device__ __forceinline__ float fast_exp2(float x) {
  float r;
  asm("v_exp_f32 %0, %1" : "=v"(r) : "v"(x));
  return r;
}
__device__ __forceinline__ float fast_rcp(float x) {
  float r;
  asm("v_rcp_f32 %0, %1" : "=v"(r) : "v"(x));
  return r;
}
// tanh-form gelu on HW exp/rcp (|err vs exact erf-gelu| < 3e-3 << 0.1 thr)
__device__ __forceinline__ float gelu_fast(float v) {
  float y = v * 0.7978845608028654f * (1.f + 0.044715f * v * v);
  float e = fast_exp2(y * 2.8853900817779268f);   // e^{2y}
  float t = (e - 1.f) * fast_rcp(e + 1.f);        // tanh(y)
  return 0.5f * v * (1.f + t);
}
__device__ __forceinline__ facc mfma16(bfrag a, bfrag b, facc c) {
  return __builtin_amdgcn_mfma_f32_16x16x32_bf16(a, b, c, 0, 0, 0);
}
__device__ __forceinline__ facc16 mfma32(bfrag a, bfrag b, facc16 c) {
  return __builtin_amdgcn_mfma_f32_32x32x16_bf16(a, b, c, 0, 0, 0);
}

union U4 { uint32_t w[4]; bfrag f; };

// Read one fragment (8 contiguous bf16 along K) from a swizzled row-major
// [rows][64] bf16 LDS tile (row stride 128 B, XOR ((row&7)<<4)).  (GEMM only)
__device__ __forceinline__ bfrag lds_frag(const u16* lds, int row, int kk, int ln) {
  int kb  = (kk << 6) + ((ln >> 4) << 4);
  int off = (row << 7) + (kb ^ ((row & 7) << 4));
  return *(const bfrag*)((const char*)lds + off);
}

// Stage a [ROWS][64] bf16 tile global->LDS via global_load_lds (16B/lane).
// NW = number of warps cooperating.  (GEMM only)
template <int ROWS, int NW>
__device__ __forceinline__ void stage_tile(const u16* gbase, int ldK, u16* lds,
                                           int wv, int ln) {
#pragma unroll
  for (int i = 0; i < ROWS / 8 / NW; i++) {
    int seg = i * NW + wv;                   // 1024-byte LDS segment
    int row = (seg << 3) + (ln >> 3);
    int kb  = (ln & 7) << 4;
    const char* g = (const char*)(gbase + (size_t)row * ldK) +
                    (kb ^ ((row & 7) << 4));
    __builtin_amdgcn_global_load_lds(GAS(g), LAS(lds + (seg << 9)), 16, 0, 0);
  }
}

// ---------------------------------------------------------------------------
// Generic GEMM: C[M,N] = epi(A[M,K] @ Bt[N,K]^T + bias)
// EPI: 0 = bf16 store, 1 = gelu+bf16, 2 = qkv scatter (q scaled, k/v frag-
//      major), 3 = f32 + residual(x)
// ---------------------------------------------------------------------------
template <int EPI, int BN>
__global__ __launch_bounds__(256) void gemm_bt(
    const u16* __restrict__ A, const u16* __restrict__ Bt,
    const float* __restrict__ bias, const float* __restrict__ resid,
    u16* __restrict__ obf, float* __restrict__ of32,
    u16* __restrict__ qb, u16* __restrict__ kb2, u16* __restrict__ vb,
    int M, int N, int K) {
  const int t = threadIdx.x, wv = t >> 6, ln = t & 63;
  const int wr = wv >> 1, wc = wv & 1;
  const int m0 = blockIdx.y << 7, n0 = blockIdx.x * BN;
  constexpr int NJ = (BN + 31) / 32;

  __shared__ __align__(16) u16 Al[128 * 64];
  __shared__ __align__(16) u16 Bl[BN * 64];

  facc acc[4][NJ];
#pragma unroll
  for (int i = 0; i < 4; i++)
#pragma unroll
    for (int j = 0; j < NJ; j++)
#pragma unroll
      for (int r = 0; r < 4; r++) acc[i][j][r] = 0.f;

  const u16* Ab = A + (size_t)m0 * K;
  const u16* Bb = Bt + (size_t)n0 * K;
  stage_tile<128, 4>(Ab, K, Al, wv, ln);
  stage_tile<BN, 4>(Bb, K, Bl, wv, ln);

  const int nk = K >> 6;
  for (int kt = 0; kt < nk; ++kt) {
    __syncthreads();
#pragma unroll
    for (int kk = 0; kk < 2; kk++) {
      bfrag av[4], bv[NJ];
#pragma unroll
      for (int i = 0; i < 4; i++)
        av[i] = lds_frag(Al, (wr << 6) + (i << 4) + (ln & 15), kk, ln);
#pragma unroll
      for (int j = 0; j < NJ; j++)
        bv[j] = lds_frag(Bl, wc * (BN / 2) + (j << 4) + (ln & 15), kk, ln);
      __builtin_amdgcn_s_setprio(1);
#pragma unroll
      for (int i = 0; i < 4; i++)
#pragma unroll
        for (int j = 0; j < NJ; j++)
          acc[i][j] = mfma16(av[i], bv[j], acc[i][j]);
      __builtin_amdgcn_s_setprio(0);
    }
    if (kt + 1 < nk) {
      __syncthreads();
      stage_tile<128, 4>(Ab + (kt + 1) * 64, K, Al, wv, ln);
      stage_tile<BN, 4>(Bb + (kt + 1) * 64, K, Bl, wv, ln);
    }
  }

  const int rb = (ln >> 4) << 2, cb = ln & 15;
#pragma unroll
  for (int i = 0; i < 4; i++) {
#pragma unroll
    for (int j = 0; j < NJ; j++) {
      const int col = n0 + wc * (BN / 2) + (j << 4) + cb;
      const float bcol = bias ? bias[col] : 0.f;
#pragma unroll
      for (int r = 0; r < 4; r++) {
        const int row = m0 + (wr << 6) + (i << 4) + rb + r;
        float val = acc[i][j][r] + bcol;
        if (EPI == 0) {
          obf[(size_t)row * N + col] = f2bf(val);
        } else if (EPI == 1) {
          obf[(size_t)row * N + col] = f2bf(gelu_fast(val));
        } else if (EPI == 2) {
          const int sec = col >> 8, cc = col & 255, h = cc >> 6, dh = cc & 63;
          const int b = row >> 12, s = row & 4095;
          const int bh = b * 4 + h;
          if (sec == 0) {
            // Q row-major [bh][s][64], pre-scaled by 0.125*log2(e)
            qb[((size_t)bh * 4096 + s) * 64 + dh] =
                f2bf(val * 0.18033688011112042f);
          } else if (sec == 1) {
            // K frag-major: [bh][s>>5][dc][lane][e]
            const int kt2 = s >> 5, kl = s & 31;
            const int dc = dh >> 4, lane = kl + ((dh >> 3) & 1) * 32, e = dh & 7;
            kb2[((size_t)bh * 128 + kt2) * 2048 + dc * 512 + lane * 8 + e] =
                f2bf(val);
          } else {
            // V frag-major: [bh][s>>5][c*2+dj][lane][e]
            const int kt2 = s >> 5, c = (s >> 4) & 1;
            const int lane = ((s >> 3) & 1) * 32 + (dh & 31), e = s & 7;
            const int dj = dh >> 5;
            vb[((size_t)bh * 128 + kt2) * 2048 + (c * 2 + dj) * 512 +
               lane * 8 + e] = f2bf(val);
          }
        } else {
          of32[(size_t)row * N + col] = val + resid[(size_t)row * N + col];
        }
      }
    }
  }
}

// ---------------------------------------------------------------------------
// Unified small weight-fusion GEMMs (one launch, sections via blockIdx.z)
// ---------------------------------------------------------------------------
__global__ __launch_bounds__(256) void wgemm5(
    const u16* __restrict__ wqkvT, const u16* __restrict__ owqkv,
    const u16* __restrict__ m0_t, const u16* __restrict__ wo_bf,
    const u16* __restrict__ opT, const u16* __restrict__ mo_bf,
    u16* __restrict__ Wqkv_t, u16* __restrict__ Wf1_t,
    u16* __restrict__ Wmo_t) {
  const int z = blockIdx.z;
  const u16 *A, *Bt; u16* out; int M, N, rowOff;
  if (z < 3)      { A = wqkvT + z * 65536; Bt = owqkv + z * 131072;
                    out = Wqkv_t; M = 256; N = 512; rowOff = z * 256; }
  else if (z == 3){ A = m0_t; Bt = wo_bf; out = Wf1_t; M = 256; N = 256; rowOff = 0; }
  else            { A = opT;  Bt = mo_bf; out = Wmo_t; M = 512; N = 256; rowOff = 0; }
  const int m0 = blockIdx.y << 7, n0 = blockIdx.x << 6;
  if (m0 >= M || n0 >= N) return;

  const int t = threadIdx.x, wv = t >> 6, ln = t & 63;
  const int wr = wv >> 1, wc = wv & 1;
  __shared__ __align__(16) u16 Al[128 * 64];
  __shared__ __align__(16) u16 Bl[64 * 64];

  facc acc[4][2];
#pragma unroll
  for (int i = 0; i < 4; i++)
#pragma unroll
    for (int j = 0; j < 2; j++)
#pragma unroll
      for (int r = 0; r < 4; r++) acc[i][j][r] = 0.f;

  const u16* Ab = A + (size_t)m0 * 256;
  const u16* Bb = Bt + (size_t)n0 * 256;
  stage_tile<128, 4>(Ab, 256, Al, wv, ln);
  stage_tile<64, 4>(Bb, 256, Bl, wv, ln);

  for (int kt = 0; kt < 4; ++kt) {
    __syncthreads();
#pragma unroll
    for (int kk = 0; kk < 2; kk++) {
      bfrag av[4], bv[2];
#pragma unroll
      for (int i = 0; i < 4; i++)
        av[i] = lds_frag(Al, (wr << 6) + (i << 4) + (ln & 15), kk, ln);
#pragma unroll
      for (int j = 0; j < 2; j++)
        bv[j] = lds_frag(Bl, wc * 32 + (j << 4) + (ln & 15), kk, ln);
#pragma unroll
      for (int i = 0; i < 4; i++)
#pragma unroll
        for (int j = 0; j < 2; j++)
          acc[i][j] = mfma16(av[i], bv[j], acc[i][j]);
    }
    if (kt + 1 < 4) {
      __syncthreads();
      stage_tile<128, 4>(Ab + (kt + 1) * 64, 256, Al, wv, ln);
      stage_tile<64, 4>(Bb + (kt + 1) * 64, 256, Bl, wv, ln);
    }
  }

  const int rb = (ln >> 4) << 2, cb = ln & 15;
#pragma unroll
  for (int i = 0; i < 4; i++)
#pragma unroll
    for (int j = 0; j < 2; j++) {
      const int col = n0 + wc * 32 + (j << 4) + cb;
#pragma unroll
      for (int r = 0; r < 4; r++) {
        const int row = m0 + (wr << 6) + (i << 4) + rb + r;
        out[(size_t)(rowOff + row) * N + col] = f2bf(acc[i][j][r]);
      }
    }
}

// ---------------------------------------------------------------------------
// Flash attention v7: SINGLE-WAVE blocks (64 thr), no barriers.
// Each wave owns 64 q rows and stages its own K+V tiles; pipeline kept full
// with counted s_waitcnt vmcnt(8) (tile k+1's 8 loads stay in flight while
// computing tile k).  Fragment-major K/V -> lane-linear LDS, 0 conflicts.
// l via P@ones MFMA.  p = v_exp_f32(s), no-max softmax, scale folded in Q.
// Q: [8][4096][64] bf16 (pre-scaled).  Kf/Vf: [8][128][2048] bf16 frag-major.
// Opart: [kvs][8][4096][64] bf16 unnormalized; lpart: [kvs][8][4096] f32.
// Grid (64, 8, kvs).
// ---------------------------------------------------------------------------
__global__ __launch_bounds__(64) void attn7(
    const u16* __restrict__ qg, const u16* __restrict__ kfg,
    const u16* __restrict__ vfg, u16* __restrict__ Opart,
    float* __restrict__ lpart, int NT) {
  const int ln = threadIdx.x;
  const int l31 = ln & 31, lh = ln >> 5;
  const int qt = blockIdx.x, bh = blockIdx.y, kv = blockIdx.z;
  const int qbase = qt * 64;
  const u16* Q  = qg + ((size_t)bh * 4096 + qbase) * 64;
  const u16* Kf = kfg + ((size_t)bh * 128 + (size_t)kv * NT) * 2048;
  const u16* Vf = vfg + ((size_t)bh * 128 + (size_t)kv * NT) * 2048;

  __shared__ __align__(16) u16 Klds[2][2048];
  __shared__ __align__(16) u16 Vlds[2][2048];

  // Q B-frags: qf[qi][dc]: lane holds Q[qbase+qi*32+l31][dc*16+lh*8 .. +8]
  bfrag qf[2][4];
#pragma unroll
  for (int qi = 0; qi < 2; qi++) {
    const u16* qp = Q + (size_t)(((qi << 5) + l31) << 6) + (lh << 3);
#pragma unroll
    for (int dc = 0; dc < 4; dc++)
      qf[qi][dc] = *(const bfrag*)(qp + (dc << 4));
  }
  bfrag ones;
#pragma unroll
  for (int j = 0; j < 8; j++) ones[j] = (short)0x3F80;

  facc16 oacc[2][2];   // [qi][dj]
  facc16 lacc[2];      // [qi] row sums via P@ones
#pragma unroll
  for (int qi = 0; qi < 2; qi++)
#pragma unroll
    for (int r = 0; r < 16; r++) {
      oacc[qi][0][r] = 0.f; oacc[qi][1][r] = 0.f; lacc[qi][r] = 0.f;
    }

  // prologue: stage tile 0 (8 x 1KB, lane-linear)
#pragma unroll
  for (int i = 0; i < 4; i++)
    __builtin_amdgcn_global_load_lds(GAS(Kf + i * 512 + ln * 8),
                                     LAS(Klds[0] + i * 512), 16, 0, 0);
#pragma unroll
  for (int i = 0; i < 4; i++)
    __builtin_amdgcn_global_load_lds(GAS(Vf + i * 512 + ln * 8),
                                     LAS(Vlds[0] + i * 512), 16, 0, 0);

  for (int kt = 0; kt < NT; ++kt) {
    const int cur = kt & 1;
    if (kt + 1 < NT) {
      // issue next tile's 8 loads, then wait until only they remain
      const u16* ksrc = Kf + (size_t)(kt + 1) * 2048;
      const u16* vsrc = Vf + (size_t)(kt + 1) * 2048;
#pragma unroll
      for (int i = 0; i < 4; i++)
        __builtin_amdgcn_global_load_lds(GAS(ksrc + i * 512 + ln * 8),
                                         LAS(Klds[cur ^ 1] + i * 512), 16, 0, 0);
#pragma unroll
      for (int i = 0; i < 4; i++)
        __builtin_amdgcn_global_load_lds(GAS(vsrc + i * 512 + ln * 8),
                                         LAS(Vlds[cur ^ 1] + i * 512), 16, 0, 0);
      asm volatile("s_waitcnt vmcnt(8)" ::: "memory");
    } else {
      asm volatile("s_waitcnt vmcnt(0)" ::: "memory");
    }
    __builtin_amdgcn_sched_barrier(0);

    // K A-frags: lane-linear reads, zero conflicts
    bfrag kf[4];
#pragma unroll
    for (int dc = 0; dc < 4; dc++)
      kf[dc] = *(const bfrag*)(Klds[cur] + dc * 512 + ln * 8);

    bfrag pa[2][2];    // [qi][k-chunk c]
#pragma unroll
    for (int qi = 0; qi < 2; qi++) {
      facc16 sa;
#pragma unroll
      for (int r = 0; r < 16; r++) sa[r] = 0.f;
      __builtin_amdgcn_s_setprio(1);
#pragma unroll
      for (int dc = 0; dc < 4; dc++)
        sa = mfma32(kf[dc], qf[qi][dc], sa);
      __builtin_amdgcn_s_setprio(0);
      // p = 2^s via raw v_exp_f32
      float p[16];
#pragma unroll
      for (int r = 0; r < 16; r++) p[r] = fast_exp2(sa[r]);
      // pack to bf16 + cross-half exchange -> PV A-frags
      uint32_t u0, u1, u2, u3, u4, u5, u6, u7;
      asm("v_cvt_pk_bf16_f32 %0, %1, %2" : "=v"(u0) : "v"(p[0]),  "v"(p[1]));
      asm("v_cvt_pk_bf16_f32 %0, %1, %2" : "=v"(u1) : "v"(p[2]),  "v"(p[3]));
      asm("v_cvt_pk_bf16_f32 %0, %1, %2" : "=v"(u2) : "v"(p[4]),  "v"(p[5]));
      asm("v_cvt_pk_bf16_f32 %0, %1, %2" : "=v"(u3) : "v"(p[6]),  "v"(p[7]));
      asm("v_cvt_pk_bf16_f32 %0, %1, %2" : "=v"(u4) : "v"(p[8]),  "v"(p[9]));
      asm("v_cvt_pk_bf16_f32 %0, %1, %2" : "=v"(u5) : "v"(p[10]), "v"(p[11]));
      asm("v_cvt_pk_bf16_f32 %0, %1, %2" : "=v"(u6) : "v"(p[12]), "v"(p[13]));
      asm("v_cvt_pk_bf16_f32 %0, %1, %2" : "=v"(u7) : "v"(p[14]), "v"(p[15]));
      asm volatile("v_permlane32_swap_b32 %0, %1" : "+v"(u0), "+v"(u2));
      asm volatile("v_permlane32_swap_b32 %0, %1" : "+v"(u1), "+v"(u3));
      asm volatile("v_permlane32_swap_b32 %0, %1" : "+v"(u4), "+v"(u6));
      asm volatile("v_permlane32_swap_b32 %0, %1" : "+v"(u5), "+v"(u7));
      U4 c0; c0.w[0] = u0; c0.w[1] = u1; c0.w[2] = u2; c0.w[3] = u3;
      U4 c1; c1.w[0] = u4; c1.w[1] = u5; c1.w[2] = u6; c1.w[3] = u7;
      pa[qi][0] = c0.f;
      pa[qi][1] = c1.f;
    }
    // O += P @ V ; l += P @ ones (V B-frags lane-linear)
#pragma unroll
    for (int c = 0; c < 2; c++) {
      bfrag vf0 = *(const bfrag*)(Vlds[cur] + (c * 2 + 0) * 512 + ln * 8);
      bfrag vf1 = *(const bfrag*)(Vlds[cur] + (c * 2 + 1) * 512 + ln * 8);
      __builtin_amdgcn_s_setprio(1);
      oacc[0][0] = mfma32(pa[0][c], vf0, oacc[0][0]);
      oacc[1][0] = mfma32(pa[1][c], vf0, oacc[1][0]);
      oacc[0][1] = mfma32(pa[0][c], vf1, oacc[0][1]);
      oacc[1][1] = mfma32(pa[1][c], vf1, oacc[1][1]);
      lacc[0] = mfma32(pa[0][c], ones, lacc[0]);
      lacc[1] = mfma32(pa[1][c], ones, lacc[1]);
      __builtin_amdgcn_s_setprio(0);
    }
  }

  // epilogue: D row = (r&3)+8*(r>>2)+4*lh, col = l31
  const size_t obase = ((size_t)kv * 8 + bh) * 4096 + qbase;
#pragma unroll
  for (int qi = 0; qi < 2; qi++) {
#pragma unroll
    for (int r = 0; r < 16; r++) {
      const int qrow = (qi << 5) + (r & 3) + ((r >> 2) << 3) + (lh << 2);
#pragma unroll
      for (int dj = 0; dj < 2; dj++)
        Opart[(obase + qrow) * 64 + (dj << 5) + l31] = f2bf(oacc[qi][dj][r]);
      if (l31 == 0) lpart[obase + qrow] = lacc[qi][r];
    }
  }
}

// ctx[b][s][h*64+d] = sum_p O_p / sum_p l_p   (np partials, runtime)
__global__ __launch_bounds__(256) void attn_combineN(
    const u16* __restrict__ Opart, const float* __restrict__ lpart,
    u16* __restrict__ ctx, int np) {
  const int idx = blockIdx.x * 256 + threadIdx.x;   // 262144 total
  const int d0 = (idx & 7) << 3, s = (idx >> 3) & 4095, bh = idx >> 15;
  const size_t sb = (size_t)bh * 4096 + s;
  float acc[8] = {0.f, 0.f, 0.f, 0.f, 0.f, 0.f, 0.f, 0.f};
  float lsum = 0.f;
  for (int pz = 0; pz < np; pz++) {
    const size_t pb = (size_t)pz * 8 * 4096;
    bfrag a = *(const bfrag*)(Opart + (pb + sb) * 64 + d0);
#pragma unroll
    for (int j = 0; j < 8; j++) acc[j] += bf2f((u16)a[j]);
    lsum += lpart[pb + sb];
  }
  const float rl = 1.f / lsum;
  bfrag o;
#pragma unroll
  for (int j = 0; j < 8; j++) o[j] = (short)f2bf(acc[j] * rl);
  *(bfrag*)(ctx + ((size_t)(bh >> 2) * 4096 + s) * 256 + ((bh & 3) << 6) + d0) = o;
}

// ---------------------------------------------------------------------------
// prep_all: all casts / transposes / bias fusions in ONE launch.
// ---------------------------------------------------------------------------
__global__ __launch_bounds__(256) void prep_all(
    const float* __restrict__ x,
    const float* __restrict__ qp, const float* __restrict__ kp,
    const float* __restrict__ vp, const float* __restrict__ mo,
    const float* __restrict__ wo,
    const float* __restrict__ wq, const float* __restrict__ wk,
    const float* __restrict__ wv, const float* __restrict__ m0,
    const float* __restrict__ m1, const float* __restrict__ op_w,
    const float* __restrict__ qp_b, const float* __restrict__ kp_b,
    const float* __restrict__ vp_b, const float* __restrict__ wq_b,
    const float* __restrict__ wk_b, const float* __restrict__ wv_b,
    const float* __restrict__ mo_b, const float* __restrict__ op_b,
    const float* __restrict__ wo_b, const float* __restrict__ m0_b,
    u16* __restrict__ xb, u16* __restrict__ owqkv, u16* __restrict__ mo_bf,
    u16* __restrict__ wo_bf, u16* __restrict__ wqkvT, u16* __restrict__ m0_t,
    u16* __restrict__ m1_t, u16* __restrict__ opT,
    float* __restrict__ bqkv, float* __restrict__ bmo,
    float* __restrict__ bf1) {
  const int bid = blockIdx.x, t = threadIdx.x;
  if (bid < 2048) {
    const size_t i = ((size_t)bid * 256 + t) * 8;
    float4 a = *(const float4*)(x + i);
    float4 b = *(const float4*)(x + i + 4);
    bfrag o;
    o[0] = (short)f2bf(a.x); o[1] = (short)f2bf(a.y);
    o[2] = (short)f2bf(a.z); o[3] = (short)f2bf(a.w);
    o[4] = (short)f2bf(b.x); o[5] = (short)f2bf(b.y);
    o[6] = (short)f2bf(b.z); o[7] = (short)f2bf(b.w);
    *(bfrag*)(xb + i) = o;
  } else if (bid < 2176) {
    const int i = (bid - 2048) * 4096 + t * 16;     // 0..524287
    const float* s; u16* dst; int off;
    if (i < 131072)      { s = qp; dst = owqkv;          off = i; }
    else if (i < 262144) { s = kp; dst = owqkv + 131072; off = i - 131072; }
    else if (i < 393216) { s = vp; dst = owqkv + 262144; off = i - 262144; }
    else if (i < 458752) { s = mo; dst = mo_bf;          off = i - 393216; }
    else                 { s = wo; dst = wo_bf;          off = i - 458752; }
    bfrag o0, o1;
#pragma unroll
    for (int q = 0; q < 2; q++) {
      float4 v0 = *(const float4*)(s + off + q * 8);
      float4 v1 = *(const float4*)(s + off + q * 8 + 4);
      bfrag& o = q ? o1 : o0;
      o[0] = (short)f2bf(v0.x); o[1] = (short)f2bf(v0.y);
      o[2] = (short)f2bf(v0.z); o[3] = (short)f2bf(v0.w);
      o[4] = (short)f2bf(v1.x); o[5] = (short)f2bf(v1.y);
      o[6] = (short)f2bf(v1.z); o[7] = (short)f2bf(v1.w);
    }
    *(bfrag*)(dst + off) = o0;
    *(bfrag*)(dst + off + 8) = o1;
  } else if (bid < 2288) {
    __shared__ float tile[64][65];
    const int tid = bid - 2176;
    const float* src; u16* dst; int r0, c0, ldS, ldD;
    if (tid < 80) {
      const int mi = tid >> 4, tt = tid & 15;
      r0 = ((tt >> 2) << 6); c0 = ((tt & 3) << 6); ldS = 256; ldD = 256;
      switch (mi) {
        case 0: src = wq; dst = wqkvT; break;
        case 1: src = wk; dst = wqkvT + 65536; break;
        case 2: src = wv; dst = wqkvT + 131072; break;
        case 3: src = m0; dst = m0_t; break;
        default: src = m1; dst = m1_t; break;
      }
    } else {
      const int tt = tid - 80;                  // 0..31
      r0 = ((tt >> 3) << 6); c0 = ((tt & 7) << 6);
      ldS = 512; ldD = 256; src = op_w; dst = opT;
    }
    {
      const int r = t >> 2, cc = (t & 3) << 4;
      const float* sp = src + (size_t)(r0 + r) * ldS + c0 + cc;
#pragma unroll
      for (int q = 0; q < 4; q++) {
        float4 v = *(const float4*)(sp + q * 4);
        tile[r][cc + q * 4 + 0] = v.x; tile[r][cc + q * 4 + 1] = v.y;
        tile[r][cc + q * 4 + 2] = v.z; tile[r][cc + q * 4 + 3] = v.w;
      }
    }
    __syncthreads();
    {
      const int cl = t >> 2, k16 = (t & 3) << 4;
      bfrag o0, o1;
#pragma unroll
      for (int j = 0; j < 8; j++) {
        o0[j] = (short)f2bf(tile[k16 + j][cl]);
        o1[j] = (short)f2bf(tile[k16 + 8 + j][cl]);
      }
      u16* dp = dst + (size_t)(c0 + cl) * ldD + r0 + k16;
      *(bfrag*)(dp) = o0;
      *(bfrag*)(dp + 8) = o1;
    }
  } else {
    const int bz = bid - 2288;
    if (bz < 3) {
      const float* ob = bz == 0 ? qp_b : (bz == 1 ? kp_b : vp_b);
      const float* iw = bz == 0 ? wq : (bz == 1 ? wk : wv);
      const float* ib = bz == 0 ? wq_b : (bz == 1 ? wk_b : wv_b);
      float s = 0.f;
      for (int c = 0; c < 256; c++) s += ob[c] * iw[(size_t)c * 256 + t];
      bqkv[bz * 256 + t] = s + ib[t];
    } else if (bz < 5) {
      const int d = (bz - 3) * 256 + t;
      float s = 0.f;
      for (int c = 0; c < 256; c++) s += mo_b[c] * op_w[(size_t)c * 512 + d];
      bmo[d] = s + op_b[d];
    } else {
      float s = 0.f;
      for (int c = 0; c < 256; c++) s += wo_b[c] * m0[(size_t)c * 256 + t];
      bf1[t] = s + m0_b[t];
    }
  }
}

// ---------------------------------------------------------------------------
extern "C" void kernel_launch(void* const* d_in, const int* in_sizes, int n_in,
                              void* d_out, int out_size, void* d_ws,
                              size_t ws_size, hipStream_t stream) {
  const float* x    = (const float*)d_in[0];
  const float* qp_w = (const float*)d_in[1];
  const float* qp_b = (const float*)d_in[2];
  const float* kp_w = (const float*)d_in[3];
  const float* kp_b = (const float*)d_in[4];
  const float* vp_w = (const float*)d_in[5];
  const float* vp_b = (const float*)d_in[6];
  const float* wq_w = (const float*)d_in[7];
  const float* wq_b = (const float*)d_in[8];
  const float* wk_w = (const float*)d_in[9];
  const float* wk_b = (const float*)d_in[10];
  const float* wv_w = (const float*)d_in[11];
  const float* wv_b = (const float*)d_in[12];
  const float* wo_w = (const float*)d_in[13];
  const float* wo_b = (const float*)d_in[14];
  const float* m0_w = (const float*)d_in[15];
  const float* m0_b = (const float*)d_in[16];
  const float* m1_w = (const float*)d_in[17];
  const float* m1_b = (const float*)d_in[18];
  const float* mo_w = (const float*)d_in[19];
  const float* mo_b = (const float*)d_in[20];
  const float* op_w = (const float*)d_in[21];
  const float* op_b = (const float*)d_in[22];
  float* out = (float*)d_out;

  // kvsplit: 8 if workspace allows (needs ~53 MB), else 4 (needs ~37 MB)
  const size_t MB = 1024 * 1024;
  const int kvs = (ws_size >= 56 * MB) ? 8 : 4;
  const int NT = 128 / kvs;           // K-tiles (32 keys) per attn block

  char* ws = (char*)d_ws;
  u16*   q_buf  = (u16*)(ws);                       //  4 MB
  u16*   kf_buf = (u16*)(ws + 4 * MB);              //  4 MB
  u16*   vf_buf = (u16*)(ws + 8 * MB);              //  4 MB
  u16*   ctx    = (u16*)(ws + 12 * MB);             //  4 MB
  u16*   xb     = (u16*)(ws + 16 * MB);             //  8 MB (dies after qkv)
  u16*   Opart  = (u16*)(ws + 16 * MB);             //  kvs*4 MB (alias xb)
  char*  wb     = ws + 16 * MB + (size_t)kvs * 4 * MB;
  u16*   owqkv  = (u16*)(wb);                       //  768 KB
  u16*   wqkvT  = (u16*)(wb + 786432);              //  384 KB
  u16*   Wqkv_t = (u16*)(wb + 1179648);             //  768 KB
  u16*   m0_t   = (u16*)(wb + 1966080);             //  128 KB
  u16*   m1_t   = (u16*)(wb + 2097152);             //  128 KB
  u16*   opT    = (u16*)(wb + 2228224);             //  256 KB
  u16*   mo_bf  = (u16*)(wb + 2490368);             //  128 KB
  u16*   wo_bf  = (u16*)(wb + 2621440);             //  128 KB
  u16*   Wf1_t  = (u16*)(wb + 2752512);             //  128 KB
  u16*   Wmo_t  = (u16*)(wb + 2883584);             //  256 KB
  float* bqkv   = (float*)(wb + 3145728);           //    3 KB
  float* bmo    = (float*)(wb + 3149824);           //    2 KB
  float* bf1    = (float*)(wb + 3151872);           //    1 KB
  float* lpart  = (float*)(wb + 3153920);           //  kvs*128 KB
  u16* h1 = q_buf;    // q dead after attn
  u16* h2 = kf_buf;   // k dead after attn

  // ---- prep (1 launch) ----
  prep_all<<<2294, 256, 0, stream>>>(
      x, qp_w, kp_w, vp_w, mo_w, wo_w,
      wq_w, wk_w, wv_w, m0_w, m1_w, op_w,
      qp_b, kp_b, vp_b, wq_b, wk_b, wv_b, mo_b, op_b, wo_b, m0_b,
      xb, owqkv, mo_bf, wo_bf, wqkvT, m0_t, m1_t, opT, bqkv, bmo, bf1);
  // ---- weight-fusion GEMMs (1 launch) ----
  wgemm5<<<dim3(8, 4, 5), 256, 0, stream>>>(
      wqkvT, owqkv, m0_t, wo_bf, opT, mo_bf, Wqkv_t, Wf1_t, Wmo_t);

  // ---- main pipeline ----
  gemm_bt<2, 64><<<dim3(12, 64), 256, 0, stream>>>(
      xb, Wqkv_t, bqkv, nullptr, nullptr, nullptr, q_buf, kf_buf, vf_buf,
      8192, 768, 512);
  attn7<<<dim3(64, 8, kvs), 64, 0, stream>>>(q_buf, kf_buf, vf_buf,
                                             Opart, lpart, NT);
  attn_combineN<<<1024, 256, 0, stream>>>(Opart, lpart, ctx, kvs);

  // h1 = gelu(ctx @ Wf1 + bf1)
  gemm_bt<1, 32><<<dim3(8, 64), 256, 0, stream>>>(
      ctx, Wf1_t, bf1, nullptr, h1, nullptr, nullptr, nullptr, nullptr,
      8192, 256, 256);
  // h2 = gelu(h1 @ m1 + m1_b)
  gemm_bt<1, 32><<<dim3(8, 64), 256, 0, stream>>>(
      h1, m1_t, m1_b, nullptr, h2, nullptr, nullptr, nullptr, nullptr,
      8192, 256, 256);
  // out = h2 @ Wmo + bmo + x
  gemm_bt<3, 64><<<dim3(8, 64), 256, 0, stream>>>(
      h2, Wmo_t, bmo, x, nullptr, out, nullptr, nullptr, nullptr,
      8192, 512, 256);
}

// Round 11
// 219.221 us; speedup vs baseline: 1.0470x; 1.0470x over previous
//
#include <hip/hip_runtime.h>
#include <cstdint>
#include <cstddef>

// ---------------------------------------------------------------------------
// MemoryLayer on MI355X: bf16 MFMA GEMMs + flash attention (no-max softmax,
// 32x32 MFMA, fragment-major K/V global layout).
// B=2, S=4096, D=512, W=256, H=4, DH=64.
// Round-10 delta vs round-9 (passed, 229us): attention is now REGISTER-staged
// (no LDS at all). Single-wave blocks made LDS a pure staging hop; frag-major
// K/V means a lane's fragment is a contiguous coalesced 16B global load. The
// compiler emits per-fragment counted vmcnt waits (finer than the whole-tile
// vmcnt(8) barrier) and ds_read latency disappears. Ping-pong reg buffers,
// loop unrolled x2 (static names, rule #20). l-sum via VALU scalars.
// (Resubmission: round-10 bench never ran - GPU acquisition timeout.)
// ---------------------------------------------------------------------------

#define GAS(p) ((const __attribute__((address_space(1))) void*)(p))
#define LAS(p) ((__attribute__((address_space(3))) void*)(p))

typedef __attribute__((ext_vector_type(8))) short bfrag;    // 8 x bf16
typedef __attribute__((ext_vector_type(4))) float facc;     // 16x16 acc
typedef __attribute__((ext_vector_type(16))) float facc16;  // 32x32 acc
typedef uint16_t u16;

__device__ __forceinline__ u16 f2bf(float f) {
  uint32_t u = __float_as_uint(f);
  u += 0x7fffu + ((u >> 16) & 1u);          // RNE
  return (u16)(u >> 16);
}
__device__ __forceinline__ float bf2f(u16 h) {
  return __uint_as_float((uint32_t)h << 16);
}
__device__ __forceinline__ float fast_exp2(float x) {
  float r;
  asm("v_exp_f32 %0, %1" : "=v"(r) : "v"(x));
  return r;
}
__device__ __forceinline__ float fast_rcp(float x) {
  float r;
  asm("v_rcp_f32 %0, %1" : "=v"(r) : "v"(x));
  return r;
}
// tanh-form gelu on HW exp/rcp (|err vs exact erf-gelu| < 3e-3 << 0.1 thr)
__device__ __forceinline__ float gelu_fast(float v) {
  float y = v * 0.7978845608028654f * (1.f + 0.044715f * v * v);
  float e = fast_exp2(y * 2.8853900817779268f);   // e^{2y}
  float t = (e - 1.f) * fast_rcp(e + 1.f);        // tanh(y)
  return 0.5f * v * (1.f + t);
}
__device__ __forceinline__ facc mfma16(bfrag a, bfrag b, facc c) {
  return __builtin_amdgcn_mfma_f32_16x16x32_bf16(a, b, c, 0, 0, 0);
}
__device__ __forceinline__ facc16 mfma32(bfrag a, bfrag b, facc16 c) {
  return __builtin_amdgcn_mfma_f32_32x32x16_bf16(a, b, c, 0, 0, 0);
}

union U4 { uint32_t w[4]; bfrag f; };

// Read one fragment (8 contiguous bf16 along K) from a swizzled row-major
// [rows][64] bf16 LDS tile (row stride 128 B, XOR ((row&7)<<4)).  (GEMM only)
__device__ __forceinline__ bfrag lds_frag(const u16* lds, int row, int kk, int ln) {
  int kb  = (kk << 6) + ((ln >> 4) << 4);
  int off = (row << 7) + (kb ^ ((row & 7) << 4));
  return *(const bfrag*)((const char*)lds + off);
}

// Stage a [ROWS][64] bf16 tile global->LDS via global_load_lds (16B/lane).
// NW = number of warps cooperating.  (GEMM only)
template <int ROWS, int NW>
__device__ __forceinline__ void stage_tile(const u16* gbase, int ldK, u16* lds,
                                           int wv, int ln) {
#pragma unroll
  for (int i = 0; i < ROWS / 8 / NW; i++) {
    int seg = i * NW + wv;                   // 1024-byte LDS segment
    int row = (seg << 3) + (ln >> 3);
    int kb  = (ln & 7) << 4;
    const char* g = (const char*)(gbase + (size_t)row * ldK) +
                    (kb ^ ((row & 7) << 4));
    __builtin_amdgcn_global_load_lds(GAS(g), LAS(lds + (seg << 9)), 16, 0, 0);
  }
}

// ---------------------------------------------------------------------------
// Generic GEMM: C[M,N] = epi(A[M,K] @ Bt[N,K]^T + bias)
// EPI: 0 = bf16 store, 1 = gelu+bf16, 2 = qkv scatter (q scaled, k/v frag-
//      major), 3 = f32 + residual(x)
// ---------------------------------------------------------------------------
template <int EPI, int BN>
__global__ __launch_bounds__(256) void gemm_bt(
    const u16* __restrict__ A, const u16* __restrict__ Bt,
    const float* __restrict__ bias, const float* __restrict__ resid,
    u16* __restrict__ obf, float* __restrict__ of32,
    u16* __restrict__ qb, u16* __restrict__ kb2, u16* __restrict__ vb,
    int M, int N, int K) {
  const int t = threadIdx.x, wv = t >> 6, ln = t & 63;
  const int wr = wv >> 1, wc = wv & 1;
  const int m0 = blockIdx.y << 7, n0 = blockIdx.x * BN;
  constexpr int NJ = (BN + 31) / 32;

  __shared__ __align__(16) u16 Al[128 * 64];
  __shared__ __align__(16) u16 Bl[BN * 64];

  facc acc[4][NJ];
#pragma unroll
  for (int i = 0; i < 4; i++)
#pragma unroll
    for (int j = 0; j < NJ; j++)
#pragma unroll
      for (int r = 0; r < 4; r++) acc[i][j][r] = 0.f;

  const u16* Ab = A + (size_t)m0 * K;
  const u16* Bb = Bt + (size_t)n0 * K;
  stage_tile<128, 4>(Ab, K, Al, wv, ln);
  stage_tile<BN, 4>(Bb, K, Bl, wv, ln);

  const int nk = K >> 6;
  for (int kt = 0; kt < nk; ++kt) {
    __syncthreads();
#pragma unroll
    for (int kk = 0; kk < 2; kk++) {
      bfrag av[4], bv[NJ];
#pragma unroll
      for (int i = 0; i < 4; i++)
        av[i] = lds_frag(Al, (wr << 6) + (i << 4) + (ln & 15), kk, ln);
#pragma unroll
      for (int j = 0; j < NJ; j++)
        bv[j] = lds_frag(Bl, wc * (BN / 2) + (j << 4) + (ln & 15), kk, ln);
      __builtin_amdgcn_s_setprio(1);
#pragma unroll
      for (int i = 0; i < 4; i++)
#pragma unroll
        for (int j = 0; j < NJ; j++)
          acc[i][j] = mfma16(av[i], bv[j], acc[i][j]);
      __builtin_amdgcn_s_setprio(0);
    }
    if (kt + 1 < nk) {
      __syncthreads();
      stage_tile<128, 4>(Ab + (kt + 1) * 64, K, Al, wv, ln);
      stage_tile<BN, 4>(Bb + (kt + 1) * 64, K, Bl, wv, ln);
    }
  }

  const int rb = (ln >> 4) << 2, cb = ln & 15;
#pragma unroll
  for (int i = 0; i < 4; i++) {
#pragma unroll
    for (int j = 0; j < NJ; j++) {
      const int col = n0 + wc * (BN / 2) + (j << 4) + cb;
      const float bcol = bias ? bias[col] : 0.f;
#pragma unroll
      for (int r = 0; r < 4; r++) {
        const int row = m0 + (wr << 6) + (i << 4) + rb + r;
        float val = acc[i][j][r] + bcol;
        if (EPI == 0) {
          obf[(size_t)row * N + col] = f2bf(val);
        } else if (EPI == 1) {
          obf[(size_t)row * N + col] = f2bf(gelu_fast(val));
        } else if (EPI == 2) {
          const int sec = col >> 8, cc = col & 255, h = cc >> 6, dh = cc & 63;
          const int b = row >> 12, s = row & 4095;
          const int bh = b * 4 + h;
          if (sec == 0) {
            // Q row-major [bh][s][64], pre-scaled by 0.125*log2(e)
            qb[((size_t)bh * 4096 + s) * 64 + dh] =
                f2bf(val * 0.18033688011112042f);
          } else if (sec == 1) {
            // K frag-major: [bh][s>>5][dc][lane][e]
            const int kt2 = s >> 5, kl = s & 31;
            const int dc = dh >> 4, lane = kl + ((dh >> 3) & 1) * 32, e = dh & 7;
            kb2[((size_t)bh * 128 + kt2) * 2048 + dc * 512 + lane * 8 + e] =
                f2bf(val);
          } else {
            // V frag-major: [bh][s>>5][c*2+dj][lane][e]
            const int kt2 = s >> 5, c = (s >> 4) & 1;
            const int lane = ((s >> 3) & 1) * 32 + (dh & 31), e = s & 7;
            const int dj = dh >> 5;
            vb[((size_t)bh * 128 + kt2) * 2048 + (c * 2 + dj) * 512 +
               lane * 8 + e] = f2bf(val);
          }
        } else {
          of32[(size_t)row * N + col] = val + resid[(size_t)row * N + col];
        }
      }
    }
  }
}

// ---------------------------------------------------------------------------
// Unified small weight-fusion GEMMs (one launch, sections via blockIdx.z)
// ---------------------------------------------------------------------------
__global__ __launch_bounds__(256) void wgemm5(
    const u16* __restrict__ wqkvT, const u16* __restrict__ owqkv,
    const u16* __restrict__ m0_t, const u16* __restrict__ wo_bf,
    const u16* __restrict__ opT, const u16* __restrict__ mo_bf,
    u16* __restrict__ Wqkv_t, u16* __restrict__ Wf1_t,
    u16* __restrict__ Wmo_t) {
  const int z = blockIdx.z;
  const u16 *A, *Bt; u16* out; int M, N, rowOff;
  if (z < 3)      { A = wqkvT + z * 65536; Bt = owqkv + z * 131072;
                    out = Wqkv_t; M = 256; N = 512; rowOff = z * 256; }
  else if (z == 3){ A = m0_t; Bt = wo_bf; out = Wf1_t; M = 256; N = 256; rowOff = 0; }
  else            { A = opT;  Bt = mo_bf; out = Wmo_t; M = 512; N = 256; rowOff = 0; }
  const int m0 = blockIdx.y << 7, n0 = blockIdx.x << 6;
  if (m0 >= M || n0 >= N) return;

  const int t = threadIdx.x, wv = t >> 6, ln = t & 63;
  const int wr = wv >> 1, wc = wv & 1;
  __shared__ __align__(16) u16 Al[128 * 64];
  __shared__ __align__(16) u16 Bl[64 * 64];

  facc acc[4][2];
#pragma unroll
  for (int i = 0; i < 4; i++)
#pragma unroll
    for (int j = 0; j < 2; j++)
#pragma unroll
      for (int r = 0; r < 4; r++) acc[i][j][r] = 0.f;

  const u16* Ab = A + (size_t)m0 * 256;
  const u16* Bb = Bt + (size_t)n0 * 256;
  stage_tile<128, 4>(Ab, 256, Al, wv, ln);
  stage_tile<64, 4>(Bb, 256, Bl, wv, ln);

  for (int kt = 0; kt < 4; ++kt) {
    __syncthreads();
#pragma unroll
    for (int kk = 0; kk < 2; kk++) {
      bfrag av[4], bv[2];
#pragma unroll
      for (int i = 0; i < 4; i++)
        av[i] = lds_frag(Al, (wr << 6) + (i << 4) + (ln & 15), kk, ln);
#pragma unroll
      for (int j = 0; j < 2; j++)
        bv[j] = lds_frag(Bl, wc * 32 + (j << 4) + (ln & 15), kk, ln);
#pragma unroll
      for (int i = 0; i < 4; i++)
#pragma unroll
        for (int j = 0; j < 2; j++)
          acc[i][j] = mfma16(av[i], bv[j], acc[i][j]);
    }
    if (kt + 1 < 4) {
      __syncthreads();
      stage_tile<128, 4>(Ab + (kt + 1) * 64, 256, Al, wv, ln);
      stage_tile<64, 4>(Bb + (kt + 1) * 64, 256, Bl, wv, ln);
    }
  }

  const int rb = (ln >> 4) << 2, cb = ln & 15;
#pragma unroll
  for (int i = 0; i < 4; i++)
#pragma unroll
    for (int j = 0; j < 2; j++) {
      const int col = n0 + wc * 32 + (j << 4) + cb;
#pragma unroll
      for (int r = 0; r < 4; r++) {
        const int row = m0 + (wr << 6) + (i << 4) + rb + r;
        out[(size_t)(rowOff + row) * N + col] = f2bf(acc[i][j][r]);
      }
    }
}

// ---------------------------------------------------------------------------
// Flash attention v8: REGISTER-staged (no LDS), single-wave blocks.
// Fragment-major K/V -> each lane's fragment is a contiguous coalesced 16B
// global load straight into VGPRs. Ping-pong reg buffers, unroll x2; the
// compiler inserts per-fragment counted vmcnt waits (QK can start when K
// lands even while V is still in flight).  l via VALU scalar sums.
// Q: [8][4096][64] bf16 (pre-scaled).  Kf/Vf: [8][128][2048] bf16 frag-major.
// Opart: [kvs][8][4096][64] bf16 unnormalized; lpart: [kvs][8][4096] f32.
// Grid (64, 8, kvs), 64 threads. NT = 128/kvs (even).
// ---------------------------------------------------------------------------
#define LOAD_KV(kf_, vf_, kt_)                                               \
  do {                                                                       \
    const u16* kp_ = Kf + (size_t)(kt_) * 2048 + (ln << 3);                  \
    const u16* vp_ = Vf + (size_t)(kt_) * 2048 + (ln << 3);                  \
    _Pragma("unroll")                                                        \
    for (int i_ = 0; i_ < 4; i_++) kf_[i_] = *(const bfrag*)(kp_ + i_ * 512);\
    _Pragma("unroll")                                                        \
    for (int i_ = 0; i_ < 4; i_++) vf_[i_] = *(const bfrag*)(vp_ + i_ * 512);\
  } while (0)

#define ATTN_TILE_STEP(kf_, vf_)                                             \
  do {                                                                       \
    bfrag pa[2][2];                                                          \
    _Pragma("unroll")                                                        \
    for (int qi = 0; qi < 2; qi++) {                                         \
      facc16 sa;                                                             \
      _Pragma("unroll")                                                      \
      for (int r = 0; r < 16; r++) sa[r] = 0.f;                              \
      __builtin_amdgcn_s_setprio(1);                                         \
      _Pragma("unroll")                                                      \
      for (int dc = 0; dc < 4; dc++)                                         \
        sa = mfma32(kf_[dc], qf[qi][dc], sa);                                \
      __builtin_amdgcn_s_setprio(0);                                         \
      float p[16];                                                           \
      float ls = 0.f;                                                        \
      _Pragma("unroll")                                                      \
      for (int r = 0; r < 16; r++) { p[r] = fast_exp2(sa[r]); ls += p[r]; }  \
      if (qi == 0) lsum0 += ls; else lsum1 += ls;                            \
      uint32_t u0, u1, u2, u3, u4, u5, u6, u7;                               \
      asm("v_cvt_pk_bf16_f32 %0, %1, %2" : "=v"(u0) : "v"(p[0]),  "v"(p[1]));\
      asm("v_cvt_pk_bf16_f32 %0, %1, %2" : "=v"(u1) : "v"(p[2]),  "v"(p[3]));\
      asm("v_cvt_pk_bf16_f32 %0, %1, %2" : "=v"(u2) : "v"(p[4]),  "v"(p[5]));\
      asm("v_cvt_pk_bf16_f32 %0, %1, %2" : "=v"(u3) : "v"(p[6]),  "v"(p[7]));\
      asm("v_cvt_pk_bf16_f32 %0, %1, %2" : "=v"(u4) : "v"(p[8]),  "v"(p[9]));\
      asm("v_cvt_pk_bf16_f32 %0, %1, %2" : "=v"(u5) : "v"(p[10]), "v"(p[11]));\
      asm("v_cvt_pk_bf16_f32 %0, %1, %2" : "=v"(u6) : "v"(p[12]), "v"(p[13]));\
      asm("v_cvt_pk_bf16_f32 %0, %1, %2" : "=v"(u7) : "v"(p[14]), "v"(p[15]));\
      asm volatile("v_permlane32_swap_b32 %0, %1" : "+v"(u0), "+v"(u2));     \
      asm volatile("v_permlane32_swap_b32 %0, %1" : "+v"(u1), "+v"(u3));     \
      asm volatile("v_permlane32_swap_b32 %0, %1" : "+v"(u4), "+v"(u6));     \
      asm volatile("v_permlane32_swap_b32 %0, %1" : "+v"(u5), "+v"(u7));     \
      U4 c0; c0.w[0] = u0; c0.w[1] = u1; c0.w[2] = u2; c0.w[3] = u3;         \
      U4 c1; c1.w[0] = u4; c1.w[1] = u5; c1.w[2] = u6; c1.w[3] = u7;         \
      pa[qi][0] = c0.f;                                                      \
      pa[qi][1] = c1.f;                                                      \
    }                                                                        \
    _Pragma("unroll")                                                        \
    for (int c = 0; c < 2; c++) {                                            \
      __builtin_amdgcn_s_setprio(1);                                         \
      oacc[0][0] = mfma32(pa[0][c], vf_[c * 2 + 0], oacc[0][0]);             \
      oacc[1][0] = mfma32(pa[1][c], vf_[c * 2 + 0], oacc[1][0]);             \
      oacc[0][1] = mfma32(pa[0][c], vf_[c * 2 + 1], oacc[0][1]);             \
      oacc[1][1] = mfma32(pa[1][c], vf_[c * 2 + 1], oacc[1][1]);             \
      __builtin_amdgcn_s_setprio(0);                                         \
    }                                                                        \
  } while (0)

__global__ __launch_bounds__(64) void attn8(
    const u16* __restrict__ qg, const u16* __restrict__ kfg,
    const u16* __restrict__ vfg, u16* __restrict__ Opart,
    float* __restrict__ lpart, int NT) {
  const int ln = threadIdx.x;
  const int l31 = ln & 31, lh = ln >> 5;
  const int qt = blockIdx.x, bh = blockIdx.y, kv = blockIdx.z;
  const int qbase = qt * 64;
  const u16* Q  = qg + ((size_t)bh * 4096 + qbase) * 64;
  const u16* Kf = kfg + ((size_t)bh * 128 + (size_t)kv * NT) * 2048;
  const u16* Vf = vfg + ((size_t)bh * 128 + (size_t)kv * NT) * 2048;

  // Q B-frags: qf[qi][dc]: lane holds Q[qbase+qi*32+l31][dc*16+lh*8 .. +8]
  bfrag qf[2][4];
#pragma unroll
  for (int qi = 0; qi < 2; qi++) {
    const u16* qp = Q + (size_t)(((qi << 5) + l31) << 6) + (lh << 3);
#pragma unroll
    for (int dc = 0; dc < 4; dc++)
      qf[qi][dc] = *(const bfrag*)(qp + (dc << 4));
  }

  facc16 oacc[2][2];   // [qi][dj]
#pragma unroll
  for (int qi = 0; qi < 2; qi++)
#pragma unroll
    for (int r = 0; r < 16; r++) { oacc[qi][0][r] = 0.f; oacc[qi][1][r] = 0.f; }
  float lsum0 = 0.f, lsum1 = 0.f;

  bfrag ka[4], va[4], kb[4], vb[4];
  LOAD_KV(ka, va, 0);
  for (int kt = 0; kt < NT; kt += 2) {
    LOAD_KV(kb, vb, kt + 1);            // NT even: kt+1 < NT always
    ATTN_TILE_STEP(ka, va);
    if (kt + 2 < NT) LOAD_KV(ka, va, kt + 2);
    ATTN_TILE_STEP(kb, vb);
  }

  // finish l: add the other lane-half
  lsum0 += __shfl_xor(lsum0, 32);
  lsum1 += __shfl_xor(lsum1, 32);

  // epilogue: D row = (r&3)+8*(r>>2)+4*lh, col = l31
  const size_t obase = ((size_t)kv * 8 + bh) * 4096 + qbase;
#pragma unroll
  for (int qi = 0; qi < 2; qi++) {
#pragma unroll
    for (int r = 0; r < 16; r++) {
      const int qrow = (qi << 5) + (r & 3) + ((r >> 2) << 3) + (lh << 2);
#pragma unroll
      for (int dj = 0; dj < 2; dj++)
        Opart[(obase + qrow) * 64 + (dj << 5) + l31] = f2bf(oacc[qi][dj][r]);
    }
    if (lh == 0)
      lpart[obase + (qi << 5) + l31] = qi == 0 ? lsum0 : lsum1;
  }
}

// ctx[b][s][h*64+d] = sum_p O_p / sum_p l_p   (np partials, runtime)
__global__ __launch_bounds__(256) void attn_combineN(
    const u16* __restrict__ Opart, const float* __restrict__ lpart,
    u16* __restrict__ ctx, int np) {
  const int idx = blockIdx.x * 256 + threadIdx.x;   // 262144 total
  const int d0 = (idx & 7) << 3, s = (idx >> 3) & 4095, bh = idx >> 15;
  const size_t sb = (size_t)bh * 4096 + s;
  float acc[8] = {0.f, 0.f, 0.f, 0.f, 0.f, 0.f, 0.f, 0.f};
  float lsum = 0.f;
  for (int pz = 0; pz < np; pz++) {
    const size_t pb = (size_t)pz * 8 * 4096;
    bfrag a = *(const bfrag*)(Opart + (pb + sb) * 64 + d0);
#pragma unroll
    for (int j = 0; j < 8; j++) acc[j] += bf2f((u16)a[j]);
    lsum += lpart[pb + sb];
  }
  const float rl = 1.f / lsum;
  bfrag o;
#pragma unroll
  for (int j = 0; j < 8; j++) o[j] = (short)f2bf(acc[j] * rl);
  *(bfrag*)(ctx + ((size_t)(bh >> 2) * 4096 + s) * 256 + ((bh & 3) << 6) + d0) = o;
}

// ---------------------------------------------------------------------------
// prep_all: all casts / transposes / bias fusions in ONE launch.
// ---------------------------------------------------------------------------
__global__ __launch_bounds__(256) void prep_all(
    const float* __restrict__ x,
    const float* __restrict__ qp, const float* __restrict__ kp,
    const float* __restrict__ vp, const float* __restrict__ mo,
    const float* __restrict__ wo,
    const float* __restrict__ wq, const float* __restrict__ wk,
    const float* __restrict__ wv, const float* __restrict__ m0,
    const float* __restrict__ m1, const float* __restrict__ op_w,
    const float* __restrict__ qp_b, const float* __restrict__ kp_b,
    const float* __restrict__ vp_b, const float* __restrict__ wq_b,
    const float* __restrict__ wk_b, const float* __restrict__ wv_b,
    const float* __restrict__ mo_b, const float* __restrict__ op_b,
    const float* __restrict__ wo_b, const float* __restrict__ m0_b,
    u16* __restrict__ xb, u16* __restrict__ owqkv, u16* __restrict__ mo_bf,
    u16* __restrict__ wo_bf, u16* __restrict__ wqkvT, u16* __restrict__ m0_t,
    u16* __restrict__ m1_t, u16* __restrict__ opT,
    float* __restrict__ bqkv, float* __restrict__ bmo,
    float* __restrict__ bf1) {
  const int bid = blockIdx.x, t = threadIdx.x;
  if (bid < 2048) {
    const size_t i = ((size_t)bid * 256 + t) * 8;
    float4 a = *(const float4*)(x + i);
    float4 b = *(const float4*)(x + i + 4);
    bfrag o;
    o[0] = (short)f2bf(a.x); o[1] = (short)f2bf(a.y);
    o[2] = (short)f2bf(a.z); o[3] = (short)f2bf(a.w);
    o[4] = (short)f2bf(b.x); o[5] = (short)f2bf(b.y);
    o[6] = (short)f2bf(b.z); o[7] = (short)f2bf(b.w);
    *(bfrag*)(xb + i) = o;
  } else if (bid < 2176) {
    const int i = (bid - 2048) * 4096 + t * 16;     // 0..524287
    const float* s; u16* dst; int off;
    if (i < 131072)      { s = qp; dst = owqkv;          off = i; }
    else if (i < 262144) { s = kp; dst = owqkv + 131072; off = i - 131072; }
    else if (i < 393216) { s = vp; dst = owqkv + 262144; off = i - 262144; }
    else if (i < 458752) { s = mo; dst = mo_bf;          off = i - 393216; }
    else                 { s = wo; dst = wo_bf;          off = i - 458752; }
    bfrag o0, o1;
#pragma unroll
    for (int q = 0; q < 2; q++) {
      float4 v0 = *(const float4*)(s + off + q * 8);
      float4 v1 = *(const float4*)(s + off + q * 8 + 4);
      bfrag& o = q ? o1 : o0;
      o[0] = (short)f2bf(v0.x); o[1] = (short)f2bf(v0.y);
      o[2] = (short)f2bf(v0.z); o[3] = (short)f2bf(v0.w);
      o[4] = (short)f2bf(v1.x); o[5] = (short)f2bf(v1.y);
      o[6] = (short)f2bf(v1.z); o[7] = (short)f2bf(v1.w);
    }
    *(bfrag*)(dst + off) = o0;
    *(bfrag*)(dst + off + 8) = o1;
  } else if (bid < 2288) {
    __shared__ float tile[64][65];
    const int tid = bid - 2176;
    const float* src; u16* dst; int r0, c0, ldS, ldD;
    if (tid < 80) {
      const int mi = tid >> 4, tt = tid & 15;
      r0 = ((tt >> 2) << 6); c0 = ((tt & 3) << 6); ldS = 256; ldD = 256;
      switch (mi) {
        case 0: src = wq; dst = wqkvT; break;
        case 1: src = wk; dst = wqkvT + 65536; break;
        case 2: src = wv; dst = wqkvT + 131072; break;
        case 3: src = m0; dst = m0_t; break;
        default: src = m1; dst = m1_t; break;
      }
    } else {
      const int tt = tid - 80;                  // 0..31
      r0 = ((tt >> 3) << 6); c0 = ((tt & 7) << 6);
      ldS = 512; ldD = 256; src = op_w; dst = opT;
    }
    {
      const int r = t >> 2, cc = (t & 3) << 4;
      const float* sp = src + (size_t)(r0 + r) * ldS + c0 + cc;
#pragma unroll
      for (int q = 0; q < 4; q++) {
        float4 v = *(const float4*)(sp + q * 4);
        tile[r][cc + q * 4 + 0] = v.x; tile[r][cc + q * 4 + 1] = v.y;
        tile[r][cc + q * 4 + 2] = v.z; tile[r][cc + q * 4 + 3] = v.w;
      }
    }
    __syncthreads();
    {
      const int cl = t >> 2, k16 = (t & 3) << 4;
      bfrag o0, o1;
#pragma unroll
      for (int j = 0; j < 8; j++) {
        o0[j] = (short)f2bf(tile[k16 + j][cl]);
        o1[j] = (short)f2bf(tile[k16 + 8 + j][cl]);
      }
      u16* dp = dst + (size_t)(c0 + cl) * ldD + r0 + k16;
      *(bfrag*)(dp) = o0;
      *(bfrag*)(dp + 8) = o1;
    }
  } else {
    const int bz = bid - 2288;
    if (bz < 3) {
      const float* ob = bz == 0 ? qp_b : (bz == 1 ? kp_b : vp_b);
      const float* iw = bz == 0 ? wq : (bz == 1 ? wk : wv);
      const float* ib = bz == 0 ? wq_b : (bz == 1 ? wk_b : wv_b);
      float s = 0.f;
      for (int c = 0; c < 256; c++) s += ob[c] * iw[(size_t)c * 256 + t];
      bqkv[bz * 256 + t] = s + ib[t];
    } else if (bz < 5) {
      const int d = (bz - 3) * 256 + t;
      float s = 0.f;
      for (int c = 0; c < 256; c++) s += mo_b[c] * op_w[(size_t)c * 512 + d];
      bmo[d] = s + op_b[d];
    } else {
      float s = 0.f;
      for (int c = 0; c < 256; c++) s += wo_b[c] * m0[(size_t)c * 256 + t];
      bf1[t] = s + m0_b[t];
    }
  }
}

// ---------------------------------------------------------------------------
extern "C" void kernel_launch(void* const* d_in, const int* in_sizes, int n_in,
                              void* d_out, int out_size, void* d_ws,
                              size_t ws_size, hipStream_t stream) {
  const float* x    = (const float*)d_in[0];
  const float* qp_w = (const float*)d_in[1];
  const float* qp_b = (const float*)d_in[2];
  const float* kp_w = (const float*)d_in[3];
  const float* kp_b = (const float*)d_in[4];
  const float* vp_w = (const float*)d_in[5];
  const float* vp_b = (const float*)d_in[6];
  const float* wq_w = (const float*)d_in[7];
  const float* wq_b = (const float*)d_in[8];
  const float* wk_w = (const float*)d_in[9];
  const float* wk_b = (const float*)d_in[10];
  const float* wv_w = (const float*)d_in[11];
  const float* wv_b = (const float*)d_in[12];
  const float* wo_w = (const float*)d_in[13];
  const float* wo_b = (const float*)d_in[14];
  const float* m0_w = (const float*)d_in[15];
  const float* m0_b = (const float*)d_in[16];
  const float* m1_w = (const float*)d_in[17];
  const float* m1_b = (const float*)d_in[18];
  const float* mo_w = (const float*)d_in[19];
  const float* mo_b = (const float*)d_in[20];
  const float* op_w = (const float*)d_in[21];
  const float* op_b = (const float*)d_in[22];
  float* out = (float*)d_out;

  // kvsplit: 8 if workspace allows (needs ~53 MB), else 4 (needs ~37 MB)
  const size_t MB = 1024 * 1024;
  const int kvs = (ws_size >= 56 * MB) ? 8 : 4;
  const int NT = 128 / kvs;           // K-tiles (32 keys) per attn block

  char* ws = (char*)d_ws;
  u16*   q_buf  = (u16*)(ws);                       //  4 MB
  u16*   kf_buf = (u16*)(ws + 4 * MB);              //  4 MB
  u16*   vf_buf = (u16*)(ws + 8 * MB);              //  4 MB
  u16*   ctx    = (u16*)(ws + 12 * MB);             //  4 MB
  u16*   xb     = (u16*)(ws + 16 * MB);             //  8 MB (dies after qkv)
  u16*   Opart  = (u16*)(ws + 16 * MB);             //  kvs*4 MB (alias xb)
  char*  wb     = ws + 16 * MB + (size_t)kvs * 4 * MB;
  u16*   owqkv  = (u16*)(wb);                       //  768 KB
  u16*   wqkvT  = (u16*)(wb + 786432);              //  384 KB
  u16*   Wqkv_t = (u16*)(wb + 1179648);             //  768 KB
  u16*   m0_t   = (u16*)(wb + 1966080);             //  128 KB
  u16*   m1_t   = (u16*)(wb + 2097152);             //  128 KB
  u16*   opT    = (u16*)(wb + 2228224);             //  256 KB
  u16*   mo_bf  = (u16*)(wb + 2490368);             //  128 KB
  u16*   wo_bf  = (u16*)(wb + 2621440);             //  128 KB
  u16*   Wf1_t  = (u16*)(wb + 2752512);             //  128 KB
  u16*   Wmo_t  = (u16*)(wb + 2883584);             //  256 KB
  float* bqkv   = (float*)(wb + 3145728);           //    3 KB
  float* bmo    = (float*)(wb + 3149824);           //    2 KB
  float* bf1    = (float*)(wb + 3151872);           //    1 KB
  float* lpart  = (float*)(wb + 3153920);           //  kvs*128 KB
  u16* h1 = q_buf;    // q dead after attn
  u16* h2 = kf_buf;   // k dead after attn

  // ---- prep (1 launch) ----
  prep_all<<<2294, 256, 0, stream>>>(
      x, qp_w, kp_w, vp_w, mo_w, wo_w,
      wq_w, wk_w, wv_w, m0_w, m1_w, op_w,
      qp_b, kp_b, vp_b, wq_b, wk_b, wv_b, mo_b, op_b, wo_b, m0_b,
      xb, owqkv, mo_bf, wo_bf, wqkvT, m0_t, m1_t, opT, bqkv, bmo, bf1);
  // ---- weight-fusion GEMMs (1 launch) ----
  wgemm5<<<dim3(8, 4, 5), 256, 0, stream>>>(
      wqkvT, owqkv, m0_t, wo_bf, opT, mo_bf, Wqkv_t, Wf1_t, Wmo_t);

  // ---- main pipeline ----
  gemm_bt<2, 64><<<dim3(12, 64), 256, 0, stream>>>(
      xb, Wqkv_t, bqkv, nullptr, nullptr, nullptr, q_buf, kf_buf, vf_buf,
      8192, 768, 512);
  attn8<<<dim3(64, 8, kvs), 64, 0, stream>>>(q_buf, kf_buf, vf_buf,
                                             Opart, lpart, NT);
  attn_combineN<<<1024, 256, 0, stream>>>(Opart, lpart, ctx, kvs);

  // h1 = gelu(ctx @ Wf1 + bf1)
  gemm_bt<1, 32><<<dim3(8, 64), 256, 0, stream>>>(
      ctx, Wf1_t, bf1, nullptr, h1, nullptr, nullptr, nullptr, nullptr,
      8192, 256, 256);
  // h2 = gelu(h1 @ m1 + m1_b)
  gemm_bt<1, 32><<<dim3(8, 64), 256, 0, stream>>>(
      h1, m1_t, m1_b, nullptr, h2, nullptr, nullptr, nullptr, nullptr,
      8192, 256, 256);
  // out = h2 @ Wmo + bmo + x
  gemm_bt<3, 64><<<dim3(8, 64), 256, 0, stream>>>(
      h2, Wmo_t, bmo, x, nullptr, out, nullptr, nullptr, nullptr,
      8192, 512, 256);
}